// Round 11
// baseline (222.733 us; speedup 1.0000x reference)
//
#include <hip/hip_runtime.h>

#define B_ 2
#define S_ 2048
#define E_ 1024
#define H_ 16
#define D_ 64

typedef short  s16x8 __attribute__((ext_vector_type(8)));
typedef float  f32x4 __attribute__((ext_vector_type(4)));
typedef unsigned short u16x4 __attribute__((ext_vector_type(4)));

__device__ __forceinline__ ushort f2bf(float f) {
    union { float f; unsigned u; } x; x.f = f;
    unsigned u = x.u + 0x7fffu + ((x.u >> 16) & 1u);   // RNE
    return (ushort)(u >> 16);
}

__device__ __forceinline__ float fast_exp2(float x) {
    float r; asm("v_exp_f32 %0, %1" : "=v"(r) : "v"(x)); return r;
}

// ---------------------------------------------------------------------------
// Fused preprocessing: cvtx (X fp32->bf16) + both weight transposes.
// blk < 4096: cvtx.  4096..4863: Wqkv transpose.  4864..5119: Wproj transpose.
// ---------------------------------------------------------------------------
__global__ __launch_bounds__(256) void prep_fused_kernel(
    const float* __restrict__ X, ushort* __restrict__ Xbf,
    const float* __restrict__ Wqkv, ushort* __restrict__ Wqkvt,
    const float* __restrict__ Wproj, ushort* __restrict__ Wprojt)
{
    __shared__ float tile[64][65];
    int blk = blockIdx.x;
    int tid = threadIdx.x;
    if (blk < 4096) {                 // ---- cvtx
        int i = (blk * 256 + tid) * 4;
        float4 v = *(const float4*)&X[i];
        u16x4 o;
        o.x = f2bf(v.x); o.y = f2bf(v.y); o.z = f2bf(v.z); o.w = f2bf(v.w);
        *(u16x4*)&Xbf[i] = o;
        return;
    }
    const float* W; ushort* Wt; int Ndim, nb;
    if (blk < 4096 + 768) { blk -= 4096; W = Wqkv;  Wt = Wqkvt;  Ndim = 3 * E_; nb = 48; }
    else                  { blk -= 4864; W = Wproj; Wt = Wprojt; Ndim = E_;     nb = 16; }
    int n0 = (blk % nb) * 64, k0 = (blk / nb) * 64;
    int c = tid & 63;
#pragma unroll
    for (int r = tid >> 6; r < 64; r += 4)
        tile[r][c] = W[(size_t)(k0 + r) * Ndim + n0 + c];
    __syncthreads();
#pragma unroll
    for (int r = tid >> 6; r < 64; r += 4)
        Wt[(size_t)(n0 + r) * E_ + k0 + c] = f2bf(tile[c][r]);
}

// ---------------------------------------------------------------------------
// Fused post-QKV prep: V transpose (blocks 0..1023) + bias pre-pack
// (blocks 1024..1551).  vtrans applies the IN-TILE KEY PERMUTATION
// pi(j) = (j&3)*16 + (j>>2) (matches attn Ps layout); prep_bias packs causal
// bf16 tiles pre-scaled by log2(e), 16 contiguous values per consumer thread.
// ---------------------------------------------------------------------------
__global__ __launch_bounds__(256) void post_qkv_kernel(
    const float* __restrict__ V, ushort* __restrict__ Vt,
    const float* __restrict__ bias, ushort* __restrict__ biasT)
{
    __shared__ float tile[64][65];
    int blk = blockIdx.x;
    int tid = threadIdx.x;
    if (blk < 1024) {                 // ---- vtrans
        int s0 = (blk & 31) * 64;
        int bh = blk >> 5;
        int b = bh >> 4, h = bh & 15;
        int d = tid & 63;
#pragma unroll
        for (int i = tid >> 6; i < 64; i += 4)
            tile[i][d] = V[((size_t)(b * S_ + s0 + i)) * E_ + h * 64 + d];
        __syncthreads();
        int lane = tid & 63, w = tid >> 6;
        int src = ((lane & 3) * 16) + (lane >> 2);   // pi(lane)
#pragma unroll
        for (int dd = w; dd < 64; dd += 4)
            Vt[((size_t)(bh * 64 + dd)) * S_ + s0 + lane] = f2bf(tile[src][dd]);
        return;
    }
    // ---- prep_bias
    int L = blk - 1024;
    int qi = (int)((sqrtf(8.0f * (float)L + 1.0f) - 1.0f) * 0.5f);
    while ((qi + 1) * (qi + 2) / 2 <= L) qi++;
    while (qi * (qi + 1) / 2 > L) qi--;
    int ki = L - qi * (qi + 1) / 2;
    int w = tid >> 6, quad = (tid >> 4) & 3, l15 = tid & 15;
    const float LOG2E = 1.4426950408889634f;
    s16x8 h0 = (s16x8){0,0,0,0,0,0,0,0}, h1 = (s16x8){0,0,0,0,0,0,0,0};
#pragma unroll
    for (int r = 0; r < 4; r++)
#pragma unroll
        for (int kt = 0; kt < 4; kt++) {
            float v = bias[(size_t)(qi * 64 + w * 16 + quad * 4 + r) * S_
                           + ki * 64 + kt * 16 + l15] * LOG2E;
            ushort u = f2bf(v);
            int idx = r * 4 + kt;
            if (idx < 8) h0[idx] = (short)u; else h1[idx - 8] = (short)u;
        }
    ushort* dst = &biasT[((size_t)L * 256 + tid) * 16];
    *(s16x8*)dst = h0;
    *(s16x8*)(dst + 8) = h1;
}

// ---------------------------------------------------------------------------
// bf16 MFMA GEMM — BK=64 + XOR-swizzled LDS via pre-swizzled global source
// (unchanged; verified in R9: dropped from 77us out of top-5).
// ---------------------------------------------------------------------------
__global__ __launch_bounds__(256) void gemm_mfma_bt(
    const ushort* __restrict__ A,    // [M][K] bf16
    const ushort* __restrict__ Bt,   // [N][K] bf16
    const float* __restrict__ bias,  // [N]
    int M, int N, int K,
    float* __restrict__ C0,
    ushort* __restrict__ Qbf, float* __restrict__ Kf32, ushort* __restrict__ Kbf,
    float* __restrict__ Vf32, int mode)
{
    __shared__ ushort As[128 * 64];
    __shared__ ushort Bs[128 * 64];
    int tid = threadIdx.x;
    int wid = tid >> 6, lane = tid & 63;
    int l15 = lane & 15, quad = lane >> 4;
    int wm = wid >> 1, wn = wid & 1;
    int row0 = blockIdx.y * 128, col0 = blockIdx.x * 128;

    int srow = tid >> 3;                         // 0..31 (row within round)
    int pk = (tid & 7) * 8;                      // physical chunk (LDS, linear)
    int sk = (((tid & 7) ^ (srow & 7)) * 8);     // logical chunk (global src)

    f32x4 acc[4][4];
#pragma unroll
    for (int mt = 0; mt < 4; mt++)
#pragma unroll
        for (int nt = 0; nt < 4; nt++) acc[mt][nt] = (f32x4){0.f, 0.f, 0.f, 0.f};

    for (int k0 = 0; k0 < K; k0 += 64) {
        __syncthreads();
#pragma unroll
        for (int c = 0; c < 4; c++) {
            int r = c * 32 + srow;
            __builtin_amdgcn_global_load_lds(
                (const __attribute__((address_space(1))) unsigned int*)
                    &A[(size_t)(row0 + r) * K + k0 + sk],
                (__attribute__((address_space(3))) unsigned int*)&As[r * 64 + pk],
                16, 0, 0);
            __builtin_amdgcn_global_load_lds(
                (const __attribute__((address_space(1))) unsigned int*)
                    &Bt[(size_t)(col0 + r) * K + k0 + sk],
                (__attribute__((address_space(3))) unsigned int*)&Bs[r * 64 + pk],
                16, 0, 0);
        }
        __syncthreads();

#pragma unroll
        for (int kk = 0; kk < 2; kk++) {
            int xc = (((kk * 4 + quad) ^ (l15 & 7)) * 8);
            s16x8 af[4], bf[4];
#pragma unroll
            for (int mt = 0; mt < 4; mt++)
                af[mt] = *(const s16x8*)&As[(wm * 64 + mt * 16 + l15) * 64 + xc];
#pragma unroll
            for (int nt = 0; nt < 4; nt++)
                bf[nt] = *(const s16x8*)&Bs[(wn * 64 + nt * 16 + l15) * 64 + xc];
#pragma unroll
            for (int mt = 0; mt < 4; mt++)
#pragma unroll
                for (int nt = 0; nt < 4; nt++)
                    acc[mt][nt] = __builtin_amdgcn_mfma_f32_16x16x32_bf16(
                        af[mt], bf[nt], acc[mt][nt], 0, 0, 0);
        }
    }

#pragma unroll
    for (int nt = 0; nt < 4; nt++) {
        int n = col0 + wn * 64 + nt * 16 + l15;
        float bv = bias[n];
        if (mode == 1) {
            int seg = n >> 10;
            int nn = n & (E_ - 1);
#pragma unroll
            for (int mt = 0; mt < 4; mt++)
#pragma unroll
                for (int r = 0; r < 4; r++) {
                    int row = row0 + wm * 64 + mt * 16 + quad * 4 + r;
                    float v = acc[mt][nt][r] + bv;
                    size_t idx = (size_t)row * E_ + nn;
                    if (seg == 0)      Qbf[idx] = f2bf(v);
                    else if (seg == 1) { Kf32[idx] = v; Kbf[idx] = f2bf(v); }
                    else               Vf32[idx] = v;
                }
        } else {
#pragma unroll
            for (int mt = 0; mt < 4; mt++)
#pragma unroll
                for (int r = 0; r < 4; r++) {
                    int row = row0 + wm * 64 + mt * 16 + quad * 4 + r;
                    C0[(size_t)row * N + n] = acc[mt][nt][r] + bv;
                }
        }
    }
}

// ---------------------------------------------------------------------------
// MFMA flash attention, fixed-reference softmax — round 16.
// R10 post-mortem: dbuf/1-barrier regressed (45.7->48.6us; staging writes
// contend with QKT reads — guide m99/m100 reproduced). REVERTED to R9's
// proven 2-barrier schedule, then applied the amortization that DID work on
// this workload (GEMM BK 32->64, R8->R9: 77-><45us): TWO key-tiles per
// staged round.  Ks/Vs[128][64]; per round: barrier -> stage both tiles
// (8 ds_write_b128/thread) -> barrier -> prefetch next round's 2 tiles ->
// compute tiles 2u, 2u+1 back-to-back from LDS.  Barrier+drain incidence
// per tile HALVES; staging cost per tile unchanged.  Uniform pairing stays:
// per block ceil((qthi+1)/2)+ceil((qtlo+1)/2) rounds, 33 tiles total.
// Invalid odd tail tile: staged with clamped source (harmless), compute
// guarded by t<=qt.  All proven pieces unchanged: Ps b64 cvt_pk pack,
// pi-permuted Vt, biasT+exp2-direct, K/V XOR chunk swizzle, bh=blk&31 XCD
// mapping.  LDS 41KB (3 blocks/CU cap; grid keeps 2).
// ---------------------------------------------------------------------------
__global__ __launch_bounds__(256) void attn_mfma_kernel(
    const ushort* __restrict__ Qbf,   // [B*S, E] bf16
    const ushort* __restrict__ Kbf,   // [B*S, E] bf16
    const ushort* __restrict__ Vt,    // [(b*H+h)*64+d][s] bf16, key-permuted
    const ushort* __restrict__ biasT, // causal-packed bf16 tiles
    ushort* __restrict__ Ctx)         // [B*S, E] bf16
{
    __shared__ ushort Ks[128][64];
    __shared__ ushort Vs[128][64];
    __shared__ ushort Ps[4][16][72];

    int blk = blockIdx.x;
    int bh = blk & 31;               // XCD = bh%8 -> K/V L2 locality
    int pr = blk >> 5;               // 0..15
    int b = bh >> 4, h = bh & 15;
    int tid = threadIdx.x;
    int wid = tid >> 6, lane = tid & 63;
    int l15 = lane & 15, quad = lane >> 4;

    int skey = tid >> 2;
    int scol = (tid & 3) * 16;       // ushort col of this thread's 16B pair
    int sc0 = ((((tid & 3) * 2) ^ (skey & 7)) * 8);
    int sc1 = sc0 ^ 8;
    const float scale_l2e = 0.18033688011112042f;   // 0.125 * log2(e)

    const size_t krow = (size_t)(b * S_ + skey) * E_ + h * 64 + scol; // + j0*E_
    const size_t vrow = (size_t)(bh * 64 + skey) * S_ + scol;        // + j0
    int rc0 = (quad ^ (l15 & 7)) * 8;

    for (int half = 0; half < 2; half++) {
        int qt = half ? pr : (31 - pr);
        int q0w = qt * 64 + wid * 16;
        int U = (qt + 2) >> 1;       // rounds of 2 tiles

        // Q fragments (A-layout)
        const size_t qbase = ((size_t)(b * S_ + q0w + l15)) * E_ + h * 64 + quad * 8;
        s16x8 qa0 = *(const s16x8*)&Qbf[qbase];
        s16x8 qa1 = *(const s16x8*)&Qbf[qbase + 32];

        f32x4 o[4];
#pragma unroll
        for (int dt = 0; dt < 4; dt++) o[dt] = (f32x4){0.f, 0.f, 0.f, 0.f};
        float lsum[4];
#pragma unroll
        for (int r = 0; r < 4; r++) lsum[r] = 0.f;

        // ---- prefetch round 0 (tiles 0 and min(1,qt)) into registers
        int t1p = (qt >= 1) ? 1 : 0;
        float4 k0a = ((const float4*)&Kbf[krow])[0];
        float4 k0b = ((const float4*)&Kbf[krow])[1];
        float4 v0a = ((const float4*)&Vt[vrow])[0];
        float4 v0b = ((const float4*)&Vt[vrow])[1];
        float4 k1a = ((const float4*)&Kbf[krow + (size_t)(t1p * 64) * E_])[0];
        float4 k1b = ((const float4*)&Kbf[krow + (size_t)(t1p * 64) * E_])[1];
        float4 v1a = ((const float4*)&Vt[vrow + t1p * 64])[0];
        float4 v1b = ((const float4*)&Vt[vrow + t1p * 64])[1];
        const ushort* bt = &biasT[((size_t)(qt * (qt + 1) / 2) * 256 + tid) * 16];
        s16x8 bn00 = *(const s16x8*)bt;
        s16x8 bn01 = *(const s16x8*)(bt + 8);
        const ushort* btp = bt + (size_t)t1p * 4096;
        s16x8 bn10 = *(const s16x8*)btp;
        s16x8 bn11 = *(const s16x8*)(btp + 8);

        for (int u = 0; u < U; u++) {
            int tb = 2 * u;
            __syncthreads();          // prior round's compute done; LDS free
            *(float4*)&Ks[skey][sc0]      = k0a;
            *(float4*)&Ks[skey][sc1]      = k0b;
            *(float4*)&Vs[skey][sc0]      = v0a;
            *(float4*)&Vs[skey][sc1]      = v0b;
            *(float4*)&Ks[64 + skey][sc0] = k1a;
            *(float4*)&Ks[64 + skey][sc1] = k1b;
            *(float4*)&Vs[64 + skey][sc0] = v1a;
            *(float4*)&Vs[64 + skey][sc1] = v1b;
            s16x8 bc[2][2];
            bc[0][0] = bn00; bc[0][1] = bn01;
            bc[1][0] = bn10; bc[1][1] = bn11;
            __syncthreads();

            // ---- prefetch round u+1 into registers (hides under compute)
            if (u + 1 < U) {
                int ta = 2 * u + 2;
                int tbn = (2 * u + 3 <= qt) ? (2 * u + 3) : qt;
                size_t ka = krow + (size_t)(ta * 64) * E_;
                size_t kb_ = krow + (size_t)(tbn * 64) * E_;
                k0a = ((const float4*)&Kbf[ka])[0];
                k0b = ((const float4*)&Kbf[ka])[1];
                v0a = ((const float4*)&Vt[vrow + ta * 64])[0];
                v0b = ((const float4*)&Vt[vrow + ta * 64])[1];
                k1a = ((const float4*)&Kbf[kb_])[0];
                k1b = ((const float4*)&Kbf[kb_])[1];
                v1a = ((const float4*)&Vt[vrow + tbn * 64])[0];
                v1b = ((const float4*)&Vt[vrow + tbn * 64])[1];
                const ushort* pa = bt + (size_t)ta * 4096;
                bn00 = *(const s16x8*)pa;
                bn01 = *(const s16x8*)(pa + 8);
                const ushort* pb = bt + (size_t)tbn * 4096;
                bn10 = *(const s16x8*)pb;
                bn11 = *(const s16x8*)(pb + 8);
            }

            // ---- compute both tiles of this round from LDS
#pragma unroll
            for (int sub = 0; sub < 2; sub++) {
                int t = tb + sub;
                if (t > qt) continue;
                int j0 = t * 64;
                bool diag = (t == qt);

                // S = Q K^T
                f32x4 s[4];
#pragma unroll
                for (int kt = 0; kt < 4; kt++) {
                    s16x8 kb0 = *(const s16x8*)&Ks[sub * 64 + kt * 16 + l15][rc0];
                    s16x8 kb1 = *(const s16x8*)&Ks[sub * 64 + kt * 16 + l15][rc0 ^ 32];
                    f32x4 acc = (f32x4){0.f, 0.f, 0.f, 0.f};
                    acc = __builtin_amdgcn_mfma_f32_16x16x32_bf16(qa0, kb0, acc, 0, 0, 0);
                    acc = __builtin_amdgcn_mfma_f32_16x16x32_bf16(qa1, kb1, acc, 0, 0, 0);
                    s[kt] = acc;
                }

                // p = exp2(s*scale + biasT); causal mask; packed b64 Ps write
#pragma unroll
                for (int r = 0; r < 4; r++) {
                    int row = q0w + quad * 4 + r;
                    float pv[4];
#pragma unroll
                    for (int kt = 0; kt < 4; kt++) {
                        int j = j0 + kt * 16 + l15;
                        int idx = r * 4 + kt;
                        ushort ub = (ushort)((idx < 8) ? bc[sub][0][idx] : bc[sub][1][idx - 8]);
                        union { unsigned u; float f; } bcv; bcv.u = ((unsigned)ub) << 16;
                        float v = fmaf(s[kt][r], scale_l2e, bcv.f);
                        float p = (diag && j > row) ? 0.f : fast_exp2(v);
                        lsum[r] += p;
                        pv[kt] = p;
                    }
                    unsigned w0, w1;
                    asm("v_cvt_pk_bf16_f32 %0, %1, %2" : "=v"(w0) : "v"(pv[0]), "v"(pv[1]));
                    asm("v_cvt_pk_bf16_f32 %0, %1, %2" : "=v"(w1) : "v"(pv[2]), "v"(pv[3]));
                    uint2 wv; wv.x = w0; wv.y = w1;
                    *(uint2*)&Ps[wid][quad * 4 + r][l15 * 4] = wv;
                }

                // O += P V (Ps wave-private: no barrier; permuted key dim)
                s16x8 pa0 = *(const s16x8*)&Ps[wid][l15][quad * 8];
                s16x8 pa1 = *(const s16x8*)&Ps[wid][l15][32 + quad * 8];
#pragma unroll
                for (int dt = 0; dt < 4; dt++) {
                    s16x8 vb0 = *(const s16x8*)&Vs[sub * 64 + dt * 16 + l15][rc0];
                    s16x8 vb1 = *(const s16x8*)&Vs[sub * 64 + dt * 16 + l15][rc0 ^ 32];
                    o[dt] = __builtin_amdgcn_mfma_f32_16x16x32_bf16(pa0, vb0, o[dt], 0, 0, 0);
                    o[dt] = __builtin_amdgcn_mfma_f32_16x16x32_bf16(pa1, vb1, o[dt], 0, 0, 0);
                }
            }
        }

        // ---- single final row-sum reduction
        float inv_l[4];
#pragma unroll
        for (int r = 0; r < 4; r++) {
            float l = lsum[r];
            l += __shfl_xor(l, 1);
            l += __shfl_xor(l, 2);
            l += __shfl_xor(l, 4);
            l += __shfl_xor(l, 8);
            inv_l[r] = 1.f / l;
        }

#pragma unroll
        for (int dt = 0; dt < 4; dt++) {
#pragma unroll
            for (int r = 0; r < 4; r++) {
                int row = q0w + quad * 4 + r;
                Ctx[((size_t)(b * S_ + row)) * E_ + h * 64 + dt * 16 + l15] =
                    f2bf(o[dt][r] * inv_l[r]);
            }
        }
    }
}

// ---------------------------------------------------------------------------
extern "C" void kernel_launch(void* const* d_in, const int* in_sizes, int n_in,
                              void* d_out, int out_size, void* d_ws, size_t ws_size,
                              hipStream_t stream) {
    const float* X     = (const float*)d_in[0];
    const float* abias = (const float*)d_in[1];
    const float* Wqkv  = (const float*)d_in[2];
    const float* bqkv  = (const float*)d_in[3];
    const float* Wproj = (const float*)d_in[4];
    const float* bproj = (const float*)d_in[5];

    const size_t plane = (size_t)B_ * S_ * E_;   // 4,194,304
    float* out  = (float*)d_out;
    float* kout = out + plane;                   // cache_key (fp32 output)
    float* vout = kout + plane;                  // cache_value (fp32 output)

    // workspace: 4 bf16 planes + weights = 42 MB (proven footprint).
    // ctxbf ALIASES xbf (X's bf16 copy is dead after the QKV GEMM).
    // biasT ALIASES wqkvt (Wqkv^T dead after the QKV GEMM; 4.3MB <= 6MB).
    ushort* xbf    = (ushort*)d_ws;
    ushort* qbf    = xbf + plane;
    ushort* kbf    = qbf + plane;
    ushort* vt     = kbf + plane;
    ushort* ctxbf  = xbf;                        // alias (see above)
    ushort* wqkvt  = vt + plane;                 // [3E][E]
    ushort* wprojt = wqkvt + (size_t)3 * E_ * E_;// [E][E]
    ushort* biasT  = wqkvt;                      // alias (see above)

    const int M = B_ * S_;

    // fused: cvtx (4096 blocks) + Wqkv^T (768) + Wproj^T (256)
    prep_fused_kernel<<<dim3(5120), 256, 0, stream>>>(
        X, xbf, Wqkv, wqkvt, Wproj, wprojt);

    gemm_mfma_bt<<<dim3(3 * E_ / 128, M / 128), 256, 0, stream>>>(
        xbf, wqkvt, bqkv, M, 3 * E_, E_,
        nullptr, qbf, kout, kbf, vout, 1);

    // fused: vtrans (1024 blocks) + bias pre-pack (528 blocks)
    post_qkv_kernel<<<dim3(1024 + 528), 256, 0, stream>>>(
        vout, vt, abias, biasT);

    // flash attention: 512 paired blocks; XCD = bh%8 for K/V L2 locality
    attn_mfma_kernel<<<dim3(B_ * H_ * 16), 256, 0, stream>>>(
        qbf, kbf, vt, biasT, ctxbf);

    gemm_mfma_bt<<<dim3(E_ / 128, M / 128), 256, 0, stream>>>(
        ctxbf, wprojt, bproj, M, E_, E_,
        out, nullptr, nullptr, nullptr, nullptr, 0);
}

// Round 12
// 214.604 us; speedup vs baseline: 1.0379x; 1.0379x over previous
//
#include <hip/hip_runtime.h>

#define B_ 2
#define S_ 2048
#define E_ 1024
#define H_ 16
#define D_ 64

typedef short  s16x8 __attribute__((ext_vector_type(8)));
typedef float  f32x4 __attribute__((ext_vector_type(4)));
typedef unsigned short u16x4 __attribute__((ext_vector_type(4)));

__device__ __forceinline__ ushort f2bf(float f) {
    union { float f; unsigned u; } x; x.f = f;
    unsigned u = x.u + 0x7fffu + ((x.u >> 16) & 1u);   // RNE
    return (ushort)(u >> 16);
}

__device__ __forceinline__ float fast_exp2(float x) {
    float r; asm("v_exp_f32 %0, %1" : "=v"(r) : "v"(x)); return r;
}

// ---------------------------------------------------------------------------
// Fused preprocessing: cvtx (X fp32->bf16) + both weight transposes.
// blk < 4096: cvtx.  4096..4863: Wqkv transpose.  4864..5119: Wproj transpose.
// ---------------------------------------------------------------------------
__global__ __launch_bounds__(256) void prep_fused_kernel(
    const float* __restrict__ X, ushort* __restrict__ Xbf,
    const float* __restrict__ Wqkv, ushort* __restrict__ Wqkvt,
    const float* __restrict__ Wproj, ushort* __restrict__ Wprojt)
{
    __shared__ float tile[64][65];
    int blk = blockIdx.x;
    int tid = threadIdx.x;
    if (blk < 4096) {                 // ---- cvtx
        int i = (blk * 256 + tid) * 4;
        float4 v = *(const float4*)&X[i];
        u16x4 o;
        o.x = f2bf(v.x); o.y = f2bf(v.y); o.z = f2bf(v.z); o.w = f2bf(v.w);
        *(u16x4*)&Xbf[i] = o;
        return;
    }
    const float* W; ushort* Wt; int Ndim, nb;
    if (blk < 4096 + 768) { blk -= 4096; W = Wqkv;  Wt = Wqkvt;  Ndim = 3 * E_; nb = 48; }
    else                  { blk -= 4864; W = Wproj; Wt = Wprojt; Ndim = E_;     nb = 16; }
    int n0 = (blk % nb) * 64, k0 = (blk / nb) * 64;
    int c = tid & 63;
#pragma unroll
    for (int r = tid >> 6; r < 64; r += 4)
        tile[r][c] = W[(size_t)(k0 + r) * Ndim + n0 + c];
    __syncthreads();
#pragma unroll
    for (int r = tid >> 6; r < 64; r += 4)
        Wt[(size_t)(n0 + r) * E_ + k0 + c] = f2bf(tile[c][r]);
}

// ---------------------------------------------------------------------------
// Fused post-QKV prep (round 17 layouts for the SWAPPED-QKT attention):
//  vtrans (blocks 0..1023): fp32 V -> bf16 Vt [(b*H+h)*64+d][s].  Within each
//   64-key tile, SLOT s holds actual key perm(s) where, with g=s>>5,
//   q=(s&31)>>3, i=s&7:  perm(s) = (2g + (i>>2))*16 + q*4 + (i&3).
//   This matches the PV A-fragment key-slot order produced in-register by
//   the swapped QK^T (lane(l15,quad) slot quad*8+i holds key kt*16+quad*4+r
//   with kt=(g*2+(i>>2)), r=i&3).
//  prep_bias (blocks 1024..1551): causal-packed bf16 tiles pre-scaled by
//   log2(e), packed in the NEW consumer order: thread (w,quad,l15) gets the
//   16 values bias[qi*64 + w*16 + l15][ki*64 + kt*16 + quad*4 + r] at
//   idx = kt*4 + r (float4-vectorized gather).
// ---------------------------------------------------------------------------
__global__ __launch_bounds__(256) void post_qkv_kernel(
    const float* __restrict__ V, ushort* __restrict__ Vt,
    const float* __restrict__ bias, ushort* __restrict__ biasT)
{
    __shared__ float tile[64][65];
    int blk = blockIdx.x;
    int tid = threadIdx.x;
    if (blk < 1024) {                 // ---- vtrans
        int s0 = (blk & 31) * 64;
        int bh = blk >> 5;
        int b = bh >> 4, h = bh & 15;
        int d = tid & 63;
#pragma unroll
        for (int i = tid >> 6; i < 64; i += 4)
            tile[i][d] = V[((size_t)(b * S_ + s0 + i)) * E_ + h * 64 + d];
        __syncthreads();
        int lane = tid & 63, w = tid >> 6;
        int g = lane >> 5, rem = lane & 31, q2 = rem >> 3, i2 = rem & 7;
        int src = (2 * g + (i2 >> 2)) * 16 + q2 * 4 + (i2 & 3);   // perm(lane)
#pragma unroll
        for (int dd = w; dd < 64; dd += 4)
            Vt[((size_t)(bh * 64 + dd)) * S_ + s0 + lane] = f2bf(tile[src][dd]);
        return;
    }
    // ---- prep_bias (new packing)
    int L = blk - 1024;
    int qi = (int)((sqrtf(8.0f * (float)L + 1.0f) - 1.0f) * 0.5f);
    while ((qi + 1) * (qi + 2) / 2 <= L) qi++;
    while (qi * (qi + 1) / 2 > L) qi--;
    int ki = L - qi * (qi + 1) / 2;
    int w = tid >> 6, quad = (tid >> 4) & 3, l15 = tid & 15;
    const float LOG2E = 1.4426950408889634f;
    s16x8 h0 = (s16x8){0,0,0,0,0,0,0,0}, h1 = (s16x8){0,0,0,0,0,0,0,0};
#pragma unroll
    for (int kt = 0; kt < 4; kt++) {
        float4 v4 = *(const float4*)&bias[(size_t)(qi * 64 + w * 16 + l15) * S_
                                          + ki * 64 + kt * 16 + quad * 4];
        ushort u0 = f2bf(v4.x * LOG2E);
        ushort u1 = f2bf(v4.y * LOG2E);
        ushort u2 = f2bf(v4.z * LOG2E);
        ushort u3 = f2bf(v4.w * LOG2E);
        if (kt < 2) {
            h0[kt * 4 + 0] = (short)u0; h0[kt * 4 + 1] = (short)u1;
            h0[kt * 4 + 2] = (short)u2; h0[kt * 4 + 3] = (short)u3;
        } else {
            h1[(kt - 2) * 4 + 0] = (short)u0; h1[(kt - 2) * 4 + 1] = (short)u1;
            h1[(kt - 2) * 4 + 2] = (short)u2; h1[(kt - 2) * 4 + 3] = (short)u3;
        }
    }
    ushort* dst = &biasT[((size_t)L * 256 + tid) * 16];
    *(s16x8*)dst = h0;
    *(s16x8*)(dst + 8) = h1;
}

// ---------------------------------------------------------------------------
// bf16 MFMA GEMM — BK=64 + XOR-swizzled LDS via pre-swizzled global source
// (unchanged; verified in R9: dropped from 77us out of top-5).
// ---------------------------------------------------------------------------
__global__ __launch_bounds__(256) void gemm_mfma_bt(
    const ushort* __restrict__ A,    // [M][K] bf16
    const ushort* __restrict__ Bt,   // [N][K] bf16
    const float* __restrict__ bias,  // [N]
    int M, int N, int K,
    float* __restrict__ C0,
    ushort* __restrict__ Qbf, float* __restrict__ Kf32, ushort* __restrict__ Kbf,
    float* __restrict__ Vf32, int mode)
{
    __shared__ ushort As[128 * 64];
    __shared__ ushort Bs[128 * 64];
    int tid = threadIdx.x;
    int wid = tid >> 6, lane = tid & 63;
    int l15 = lane & 15, quad = lane >> 4;
    int wm = wid >> 1, wn = wid & 1;
    int row0 = blockIdx.y * 128, col0 = blockIdx.x * 128;

    int srow = tid >> 3;                         // 0..31 (row within round)
    int pk = (tid & 7) * 8;                      // physical chunk (LDS, linear)
    int sk = (((tid & 7) ^ (srow & 7)) * 8);     // logical chunk (global src)

    f32x4 acc[4][4];
#pragma unroll
    for (int mt = 0; mt < 4; mt++)
#pragma unroll
        for (int nt = 0; nt < 4; nt++) acc[mt][nt] = (f32x4){0.f, 0.f, 0.f, 0.f};

    for (int k0 = 0; k0 < K; k0 += 64) {
        __syncthreads();
#pragma unroll
        for (int c = 0; c < 4; c++) {
            int r = c * 32 + srow;
            __builtin_amdgcn_global_load_lds(
                (const __attribute__((address_space(1))) unsigned int*)
                    &A[(size_t)(row0 + r) * K + k0 + sk],
                (__attribute__((address_space(3))) unsigned int*)&As[r * 64 + pk],
                16, 0, 0);
            __builtin_amdgcn_global_load_lds(
                (const __attribute__((address_space(1))) unsigned int*)
                    &Bt[(size_t)(col0 + r) * K + k0 + sk],
                (__attribute__((address_space(3))) unsigned int*)&Bs[r * 64 + pk],
                16, 0, 0);
        }
        __syncthreads();

#pragma unroll
        for (int kk = 0; kk < 2; kk++) {
            int xc = (((kk * 4 + quad) ^ (l15 & 7)) * 8);
            s16x8 af[4], bf[4];
#pragma unroll
            for (int mt = 0; mt < 4; mt++)
                af[mt] = *(const s16x8*)&As[(wm * 64 + mt * 16 + l15) * 64 + xc];
#pragma unroll
            for (int nt = 0; nt < 4; nt++)
                bf[nt] = *(const s16x8*)&Bs[(wn * 64 + nt * 16 + l15) * 64 + xc];
#pragma unroll
            for (int mt = 0; mt < 4; mt++)
#pragma unroll
                for (int nt = 0; nt < 4; nt++)
                    acc[mt][nt] = __builtin_amdgcn_mfma_f32_16x16x32_bf16(
                        af[mt], bf[nt], acc[mt][nt], 0, 0, 0);
        }
    }

#pragma unroll
    for (int nt = 0; nt < 4; nt++) {
        int n = col0 + wn * 64 + nt * 16 + l15;
        float bv = bias[n];
        if (mode == 1) {
            int seg = n >> 10;
            int nn = n & (E_ - 1);
#pragma unroll
            for (int mt = 0; mt < 4; mt++)
#pragma unroll
                for (int r = 0; r < 4; r++) {
                    int row = row0 + wm * 64 + mt * 16 + quad * 4 + r;
                    float v = acc[mt][nt][r] + bv;
                    size_t idx = (size_t)row * E_ + nn;
                    if (seg == 0)      Qbf[idx] = f2bf(v);
                    else if (seg == 1) { Kf32[idx] = v; Kbf[idx] = f2bf(v); }
                    else               Vf32[idx] = v;
                }
        } else {
#pragma unroll
            for (int mt = 0; mt < 4; mt++)
#pragma unroll
                for (int r = 0; r < 4; r++) {
                    int row = row0 + wm * 64 + mt * 16 + quad * 4 + r;
                    C0[(size_t)row * N + n] = acc[mt][nt][r] + bv;
                }
        }
    }
}

// ---------------------------------------------------------------------------
// MFMA flash attention — round 17: SWAPPED QK^T, softmax fully in-register.
// Base schedule = R9's proven 45.7us loop (512 uniform paired blocks, 4
// waves, single-buffered K/V staging, 2 barriers/tile, reg prefetch t+1).
// R10 (dbuf) and R11 (2-tile rounds) both regressed -> cadence is optimal;
// the gate is the per-tile serial chain.  This round removes its LDS leg:
//  - QK^T computed as mfma(kb, qa) (A/B per-lane layouts are identical for
//    16x16x32, so kb/qa loads are unchanged).  Result S^T: lane(l15,quad)
//    reg r holds S[key=j0+kt*16+quad*4+r][qrow=q0w+l15] — each lane owns 16
//    P-values of ONE q-row.
//  - P never touches LDS: 8 cvt_pk pack pa0/pa1 directly (Ps buffer DELETED;
//    LDS 41->16.5KB; the 0.54M residual bank conflicts were Ps).
//    PV A-frag slot (quad*8+i) <-> key kt*16+quad*4+r order is absorbed by
//    vtrans' new perm (see post_qkv_kernel).
//  - biasT consumed in the new per-lane order idx=kt*4+r (repacked in prep).
//  - lsum: one scalar/lane; final reduce = 2 shfl_xor(16,32) + 4 shfl
//    broadcasts to map row sums to the output fragment's rows.
// ---------------------------------------------------------------------------
__global__ __launch_bounds__(256) void attn_mfma_kernel(
    const ushort* __restrict__ Qbf,   // [B*S, E] bf16
    const ushort* __restrict__ Kbf,   // [B*S, E] bf16
    const ushort* __restrict__ Vt,    // [(b*H+h)*64+d][s] bf16, key-permuted
    const ushort* __restrict__ biasT, // causal-packed bf16 tiles (new order)
    ushort* __restrict__ Ctx)         // [B*S, E] bf16
{
    __shared__ ushort Ks[64][64];
    __shared__ ushort Vs[64][64];

    int blk = blockIdx.x;
    int bh = blk & 31;               // XCD = bh%8 -> K/V L2 locality
    int pr = blk >> 5;               // 0..15
    int b = bh >> 4, h = bh & 15;
    int tid = threadIdx.x;
    int wid = tid >> 6, lane = tid & 63;
    int l15 = lane & 15, quad = lane >> 4;

    int skey = tid >> 2;
    int scol = (tid & 3) * 16;       // ushort col of this thread's 16B pair
    int sc0 = ((((tid & 3) * 2) ^ (skey & 7)) * 8);
    int sc1 = sc0 ^ 8;
    const float scale_l2e = 0.18033688011112042f;   // 0.125 * log2(e)

    const size_t krow = (size_t)(b * S_ + skey) * E_ + h * 64 + scol; // + j0*E_
    const size_t vrow = (size_t)(bh * 64 + skey) * S_ + scol;        // + j0
    int rc0 = (quad ^ (l15 & 7)) * 8;

    for (int half = 0; half < 2; half++) {
        int qt = half ? pr : (31 - pr);
        int q0w = qt * 64 + wid * 16;
        int rowq = q0w + l15;        // this lane's q-row

        // Q fragments (consumed as the B-operand of the swapped QK^T)
        const size_t qbase = ((size_t)(b * S_ + q0w + l15)) * E_ + h * 64 + quad * 8;
        s16x8 qa0 = *(const s16x8*)&Qbf[qbase];
        s16x8 qa1 = *(const s16x8*)&Qbf[qbase + 32];

        f32x4 o[4];
#pragma unroll
        for (int dt = 0; dt < 4; dt++) o[dt] = (f32x4){0.f, 0.f, 0.f, 0.f};
        float ls = 0.f;

        // ---- preload tile 0 into registers
        float4 kr0 = ((const float4*)&Kbf[krow])[0];
        float4 kr1 = ((const float4*)&Kbf[krow])[1];
        float4 vr0 = ((const float4*)&Vt[vrow])[0];
        float4 vr1 = ((const float4*)&Vt[vrow])[1];
        const ushort* bt = &biasT[((size_t)(qt * (qt + 1) / 2) * 256 + tid) * 16];
        s16x8 bn0 = *(const s16x8*)bt;
        s16x8 bn1 = *(const s16x8*)(bt + 8);

        for (int t = 0; t <= qt; t++) {
            int j0 = t * 64;
            __syncthreads();          // prior compute done; LDS free
            *(float4*)&Ks[skey][sc0] = kr0;
            *(float4*)&Ks[skey][sc1] = kr1;
            *(float4*)&Vs[skey][sc0] = vr0;
            *(float4*)&Vs[skey][sc1] = vr1;
            s16x8 b0 = bn0, b1 = bn1;
            __syncthreads();

            // ---- prefetch tile t+1 (registers only; hides under compute)
            if (t < qt) {
                int j1 = j0 + 64;
                kr0 = ((const float4*)&Kbf[krow + (size_t)j1 * E_])[0];
                kr1 = ((const float4*)&Kbf[krow + (size_t)j1 * E_])[1];
                vr0 = ((const float4*)&Vt[vrow + j1])[0];
                vr1 = ((const float4*)&Vt[vrow + j1])[1];
                const ushort* btn = bt + (size_t)(t + 1) * 4096;
                bn0 = *(const s16x8*)btn;
                bn1 = *(const s16x8*)(btn + 8);
            }

            // ---- S^T = K Q^T : lane reg r = S[key=j0+kt*16+quad*4+r][rowq]
            f32x4 s[4];
#pragma unroll
            for (int kt = 0; kt < 4; kt++) {
                s16x8 kb0 = *(const s16x8*)&Ks[kt * 16 + l15][rc0];
                s16x8 kb1 = *(const s16x8*)&Ks[kt * 16 + l15][rc0 ^ 32];
                f32x4 acc = (f32x4){0.f, 0.f, 0.f, 0.f};
                acc = __builtin_amdgcn_mfma_f32_16x16x32_bf16(kb0, qa0, acc, 0, 0, 0);
                acc = __builtin_amdgcn_mfma_f32_16x16x32_bf16(kb1, qa1, acc, 0, 0, 0);
                s[kt] = acc;
            }

            // ---- p = exp2(s*scale + biasT); causal mask; pack pa IN REGS
            bool diag = (t == qt);
            unsigned upk[8];
#pragma unroll
            for (int kt = 0; kt < 4; kt++) {
                float pv[4];
#pragma unroll
                for (int r = 0; r < 4; r++) {
                    int idx = kt * 4 + r;
                    ushort ub = (ushort)((idx < 8) ? b0[idx] : b1[idx - 8]);
                    union { unsigned u; float f; } bc; bc.u = ((unsigned)ub) << 16;
                    float v = fmaf(s[kt][r], scale_l2e, bc.f);
                    int j = j0 + kt * 16 + quad * 4 + r;
                    float p = (diag && j > rowq) ? 0.f : fast_exp2(v);
                    ls += p;
                    pv[r] = p;
                }
                asm("v_cvt_pk_bf16_f32 %0, %1, %2"
                    : "=v"(upk[kt * 2]) : "v"(pv[0]), "v"(pv[1]));
                asm("v_cvt_pk_bf16_f32 %0, %1, %2"
                    : "=v"(upk[kt * 2 + 1]) : "v"(pv[2]), "v"(pv[3]));
            }
            uint4 ua = make_uint4(upk[0], upk[1], upk[2], upk[3]);
            uint4 ub4 = make_uint4(upk[4], upk[5], upk[6], upk[7]);
            s16x8 pa0 = *(s16x8*)&ua;
            s16x8 pa1 = *(s16x8*)&ub4;

            // ---- O += P V  (A-frag from regs; V slot order = perm, set in
            //      vtrans, matches pa's key-slot order)
#pragma unroll
            for (int dt = 0; dt < 4; dt++) {
                s16x8 vb0 = *(const s16x8*)&Vs[dt * 16 + l15][rc0];
                s16x8 vb1 = *(const s16x8*)&Vs[dt * 16 + l15][rc0 ^ 32];
                o[dt] = __builtin_amdgcn_mfma_f32_16x16x32_bf16(pa0, vb0, o[dt], 0, 0, 0);
                o[dt] = __builtin_amdgcn_mfma_f32_16x16x32_bf16(pa1, vb1, o[dt], 0, 0, 0);
            }
        }

        // ---- row-sum reduction: quad-partial sums live per lane
        float l = ls;
        l += __shfl_xor(l, 16);
        l += __shfl_xor(l, 32);
        float inv = 1.f / l;          // row q0w + l15 total (all quads)
        float inv_l[4];
#pragma unroll
        for (int r = 0; r < 4; r++)
            inv_l[r] = __shfl(inv, quad * 4 + r);   // row sums for output rows

#pragma unroll
        for (int dt = 0; dt < 4; dt++) {
#pragma unroll
            for (int r = 0; r < 4; r++) {
                int row = q0w + quad * 4 + r;
                Ctx[((size_t)(b * S_ + row)) * E_ + h * 64 + dt * 16 + l15] =
                    f2bf(o[dt][r] * inv_l[r]);
            }
        }
    }
}

// ---------------------------------------------------------------------------
extern "C" void kernel_launch(void* const* d_in, const int* in_sizes, int n_in,
                              void* d_out, int out_size, void* d_ws, size_t ws_size,
                              hipStream_t stream) {
    const float* X     = (const float*)d_in[0];
    const float* abias = (const float*)d_in[1];
    const float* Wqkv  = (const float*)d_in[2];
    const float* bqkv  = (const float*)d_in[3];
    const float* Wproj = (const float*)d_in[4];
    const float* bproj = (const float*)d_in[5];

    const size_t plane = (size_t)B_ * S_ * E_;   // 4,194,304
    float* out  = (float*)d_out;
    float* kout = out + plane;                   // cache_key (fp32 output)
    float* vout = kout + plane;                  // cache_value (fp32 output)

    // workspace: 4 bf16 planes + weights = 42 MB (proven footprint).
    // ctxbf ALIASES xbf (X's bf16 copy is dead after the QKV GEMM).
    // biasT ALIASES wqkvt (Wqkv^T dead after the QKV GEMM; 4.3MB <= 6MB).
    ushort* xbf    = (ushort*)d_ws;
    ushort* qbf    = xbf + plane;
    ushort* kbf    = qbf + plane;
    ushort* vt     = kbf + plane;
    ushort* ctxbf  = xbf;                        // alias (see above)
    ushort* wqkvt  = vt + plane;                 // [3E][E]
    ushort* wprojt = wqkvt + (size_t)3 * E_ * E_;// [E][E]
    ushort* biasT  = wqkvt;                      // alias (see above)

    const int M = B_ * S_;

    // fused: cvtx (4096 blocks) + Wqkv^T (768) + Wproj^T (256)
    prep_fused_kernel<<<dim3(5120), 256, 0, stream>>>(
        X, xbf, Wqkv, wqkvt, Wproj, wprojt);

    gemm_mfma_bt<<<dim3(3 * E_ / 128, M / 128), 256, 0, stream>>>(
        xbf, wqkvt, bqkv, M, 3 * E_, E_,
        nullptr, qbf, kout, kbf, vout, 1);

    // fused: vtrans (1024 blocks, new perm) + bias pre-pack (528, new order)
    post_qkv_kernel<<<dim3(1024 + 528), 256, 0, stream>>>(
        vout, vt, abias, biasT);

    // flash attention: 512 paired blocks; XCD = bh%8 for K/V L2 locality
    attn_mfma_kernel<<<dim3(B_ * H_ * 16), 256, 0, stream>>>(
        qbf, kbf, vt, biasT, ctxbf);

    gemm_mfma_bt<<<dim3(E_ / 128, M / 128), 256, 0, stream>>>(
        ctxbf, wprojt, bproj, M, E_, E_,
        out, nullptr, nullptr, nullptr, nullptr, 0);
}

// Round 13
// 210.369 us; speedup vs baseline: 1.0588x; 1.0201x over previous
//
#include <hip/hip_runtime.h>

#define B_ 2
#define S_ 2048
#define E_ 1024
#define H_ 16
#define D_ 64

typedef short  s16x8 __attribute__((ext_vector_type(8)));
typedef float  f32x4 __attribute__((ext_vector_type(4)));
typedef unsigned short u16x4 __attribute__((ext_vector_type(4)));

__device__ __forceinline__ ushort f2bf(float f) {
    union { float f; unsigned u; } x; x.f = f;
    unsigned u = x.u + 0x7fffu + ((x.u >> 16) & 1u);   // RNE
    return (ushort)(u >> 16);
}

__device__ __forceinline__ float fast_exp2(float x) {
    float r; asm("v_exp_f32 %0, %1" : "=v"(r) : "v"(x)); return r;
}

// ---------------------------------------------------------------------------
// Fused preprocessing: cvtx (X fp32->bf16) + both weight transposes.
// blk < 4096: cvtx.  4096..4863: Wqkv transpose.  4864..5119: Wproj transpose.
// ---------------------------------------------------------------------------
__global__ __launch_bounds__(256) void prep_fused_kernel(
    const float* __restrict__ X, ushort* __restrict__ Xbf,
    const float* __restrict__ Wqkv, ushort* __restrict__ Wqkvt,
    const float* __restrict__ Wproj, ushort* __restrict__ Wprojt)
{
    __shared__ float tile[64][65];
    int blk = blockIdx.x;
    int tid = threadIdx.x;
    if (blk < 4096) {                 // ---- cvtx
        int i = (blk * 256 + tid) * 4;
        float4 v = *(const float4*)&X[i];
        u16x4 o;
        o.x = f2bf(v.x); o.y = f2bf(v.y); o.z = f2bf(v.z); o.w = f2bf(v.w);
        *(u16x4*)&Xbf[i] = o;
        return;
    }
    const float* W; ushort* Wt; int Ndim, nb;
    if (blk < 4096 + 768) { blk -= 4096; W = Wqkv;  Wt = Wqkvt;  Ndim = 3 * E_; nb = 48; }
    else                  { blk -= 4864; W = Wproj; Wt = Wprojt; Ndim = E_;     nb = 16; }
    int n0 = (blk % nb) * 64, k0 = (blk / nb) * 64;
    int c = tid & 63;
#pragma unroll
    for (int r = tid >> 6; r < 64; r += 4)
        tile[r][c] = W[(size_t)(k0 + r) * Ndim + n0 + c];
    __syncthreads();
#pragma unroll
    for (int r = tid >> 6; r < 64; r += 4)
        Wt[(size_t)(n0 + r) * E_ + k0 + c] = f2bf(tile[c][r]);
}

// ---------------------------------------------------------------------------
// prep_bias (now standalone; vtrans moved into the QKV GEMM epilogue):
// causal-packed bf16 tiles pre-scaled by log2(e), packed in the swapped-QKT
// consumer order: thread (w,quad,l15) gets the 16 values
// bias[qi*64 + w*16 + l15][ki*64 + kt*16 + quad*4 + r] at idx = kt*4 + r.
// ---------------------------------------------------------------------------
__global__ __launch_bounds__(256) void prep_bias_kernel(
    const float* __restrict__ bias, ushort* __restrict__ biasT)
{
    int L = blockIdx.x;
    int qi = (int)((sqrtf(8.0f * (float)L + 1.0f) - 1.0f) * 0.5f);
    while ((qi + 1) * (qi + 2) / 2 <= L) qi++;
    while (qi * (qi + 1) / 2 > L) qi--;
    int ki = L - qi * (qi + 1) / 2;
    int tid = threadIdx.x;
    int w = tid >> 6, quad = (tid >> 4) & 3, l15 = tid & 15;
    const float LOG2E = 1.4426950408889634f;
    s16x8 h0 = (s16x8){0,0,0,0,0,0,0,0}, h1 = (s16x8){0,0,0,0,0,0,0,0};
#pragma unroll
    for (int kt = 0; kt < 4; kt++) {
        float4 v4 = *(const float4*)&bias[(size_t)(qi * 64 + w * 16 + l15) * S_
                                          + ki * 64 + kt * 16 + quad * 4];
        ushort u0 = f2bf(v4.x * LOG2E);
        ushort u1 = f2bf(v4.y * LOG2E);
        ushort u2 = f2bf(v4.z * LOG2E);
        ushort u3 = f2bf(v4.w * LOG2E);
        if (kt < 2) {
            h0[kt * 4 + 0] = (short)u0; h0[kt * 4 + 1] = (short)u1;
            h0[kt * 4 + 2] = (short)u2; h0[kt * 4 + 3] = (short)u3;
        } else {
            h1[(kt - 2) * 4 + 0] = (short)u0; h1[(kt - 2) * 4 + 1] = (short)u1;
            h1[(kt - 2) * 4 + 2] = (short)u2; h1[(kt - 2) * 4 + 3] = (short)u3;
        }
    }
    ushort* dst = &biasT[((size_t)L * 256 + tid) * 16];
    *(s16x8*)dst = h0;
    *(s16x8*)(dst + 8) = h1;
}

// ---------------------------------------------------------------------------
// bf16 MFMA GEMM (QKV): BK=64 + XOR-swizzled LDS via pre-swizzled global
// source (R9-verified: conflicts=0).  Round-18 change: vtrans FUSED into the
// seg==2 epilogue — writes Vf32 (cache output) AND Vt bf16 directly at the
// perm-inverse slot: for in-tile key k = mt*16+quad*4+r,
//   slot = (mt>>1)*32 + quad*8 + (mt&1)*4 + r   (perm(slot)==k, verified vs
// R12's vtrans).  4 consecutive r -> one 8B packed store via 2x cvt_pk.
// ---------------------------------------------------------------------------
__global__ __launch_bounds__(256) void gemm_mfma_bt(
    const ushort* __restrict__ A,    // [M][K] bf16
    const ushort* __restrict__ Bt,   // [N][K] bf16
    const float* __restrict__ bias,  // [N]
    int M, int N, int K,
    ushort* __restrict__ Qbf, float* __restrict__ Kf32, ushort* __restrict__ Kbf,
    float* __restrict__ Vf32, ushort* __restrict__ Vt)
{
    __shared__ ushort As[128 * 64];
    __shared__ ushort Bs[128 * 64];
    int tid = threadIdx.x;
    int wid = tid >> 6, lane = tid & 63;
    int l15 = lane & 15, quad = lane >> 4;
    int wm = wid >> 1, wn = wid & 1;
    int row0 = blockIdx.y * 128, col0 = blockIdx.x * 128;

    int srow = tid >> 3;                         // 0..31 (row within round)
    int pk = (tid & 7) * 8;                      // physical chunk (LDS, linear)
    int sk = (((tid & 7) ^ (srow & 7)) * 8);     // logical chunk (global src)

    f32x4 acc[4][4];
#pragma unroll
    for (int mt = 0; mt < 4; mt++)
#pragma unroll
        for (int nt = 0; nt < 4; nt++) acc[mt][nt] = (f32x4){0.f, 0.f, 0.f, 0.f};

    for (int k0 = 0; k0 < K; k0 += 64) {
        __syncthreads();
#pragma unroll
        for (int c = 0; c < 4; c++) {
            int r = c * 32 + srow;
            __builtin_amdgcn_global_load_lds(
                (const __attribute__((address_space(1))) unsigned int*)
                    &A[(size_t)(row0 + r) * K + k0 + sk],
                (__attribute__((address_space(3))) unsigned int*)&As[r * 64 + pk],
                16, 0, 0);
            __builtin_amdgcn_global_load_lds(
                (const __attribute__((address_space(1))) unsigned int*)
                    &Bt[(size_t)(col0 + r) * K + k0 + sk],
                (__attribute__((address_space(3))) unsigned int*)&Bs[r * 64 + pk],
                16, 0, 0);
        }
        __syncthreads();

#pragma unroll
        for (int kk = 0; kk < 2; kk++) {
            int xc = (((kk * 4 + quad) ^ (l15 & 7)) * 8);
            s16x8 af[4], bf[4];
#pragma unroll
            for (int mt = 0; mt < 4; mt++)
                af[mt] = *(const s16x8*)&As[(wm * 64 + mt * 16 + l15) * 64 + xc];
#pragma unroll
            for (int nt = 0; nt < 4; nt++)
                bf[nt] = *(const s16x8*)&Bs[(wn * 64 + nt * 16 + l15) * 64 + xc];
#pragma unroll
            for (int mt = 0; mt < 4; mt++)
#pragma unroll
                for (int nt = 0; nt < 4; nt++)
                    acc[mt][nt] = __builtin_amdgcn_mfma_f32_16x16x32_bf16(
                        af[mt], bf[nt], acc[mt][nt], 0, 0, 0);
        }
    }

#pragma unroll
    for (int nt = 0; nt < 4; nt++) {
        int n = col0 + wn * 64 + nt * 16 + l15;
        float bv = bias[n];
        int seg = n >> 10;
        int nn = n & (E_ - 1);
#pragma unroll
        for (int mt = 0; mt < 4; mt++) {
            float v4[4];
#pragma unroll
            for (int r = 0; r < 4; r++) {
                int row = row0 + wm * 64 + mt * 16 + quad * 4 + r;
                float v = acc[mt][nt][r] + bv;
                v4[r] = v;
                size_t idx = (size_t)row * E_ + nn;
                if (seg == 0)      Qbf[idx] = f2bf(v);
                else if (seg == 1) { Kf32[idx] = v; Kbf[idx] = f2bf(v); }
                else               Vf32[idx] = v;
            }
            if (seg == 2) {
                // fused vtrans: bh = b*16+h, d = nn&63; key tile row0/64+wm;
                // slot = (mt>>1)*32 + quad*8 + (mt&1)*4 + r (r contiguous)
                int row_base = row0 + wm * 64;
                int b = row_base >> 11;
                int h = nn >> 6, d = nn & 63;
                int stile = (row_base & 2047) >> 6;
                int slot = ((mt >> 1) * 32) + quad * 8 + ((mt & 1) * 4);
                unsigned w0, w1;
                asm("v_cvt_pk_bf16_f32 %0, %1, %2" : "=v"(w0) : "v"(v4[0]), "v"(v4[1]));
                asm("v_cvt_pk_bf16_f32 %0, %1, %2" : "=v"(w1) : "v"(v4[2]), "v"(v4[3]));
                uint2 wv; wv.x = w0; wv.y = w1;
                size_t vtidx = ((size_t)((b * 16 + h) * 64 + d)) * S_
                               + stile * 64 + slot;
                *(uint2*)&Vt[vtidx] = wv;
            }
        }
    }
}

// ---------------------------------------------------------------------------
// Proj GEMM — round 18: 64x128 tiles for residency.  The 128x128 proj grid
// was 256 blocks = exactly 1 block/CU: zero inter-block latency hiding (the
// only kernel in the pipeline without co-residency).  BM=64, BN=128, BK=64
// -> grid 512 = 2 blocks/CU, LDS 24KB, acc[2][4].  Same XOR swizzle.
// ---------------------------------------------------------------------------
__global__ __launch_bounds__(256) void gemm_proj64(
    const ushort* __restrict__ A,    // [M][K] bf16 (ctx)
    const ushort* __restrict__ Bt,   // [N][K] bf16 (Wproj^T)
    const float* __restrict__ bias,  // [N]
    int M, int N, int K,
    float* __restrict__ C0)
{
    __shared__ ushort As[64 * 64];
    __shared__ ushort Bs[128 * 64];
    int tid = threadIdx.x;
    int wid = tid >> 6, lane = tid & 63;
    int l15 = lane & 15, quad = lane >> 4;
    int wm = wid >> 1, wn = wid & 1;
    int row0 = blockIdx.y * 64, col0 = blockIdx.x * 128;

    int srow = tid >> 3;                         // 0..31
    int pk = (tid & 7) * 8;
    int sk = (((tid & 7) ^ (srow & 7)) * 8);

    f32x4 acc[2][4];
#pragma unroll
    for (int mt = 0; mt < 2; mt++)
#pragma unroll
        for (int nt = 0; nt < 4; nt++) acc[mt][nt] = (f32x4){0.f, 0.f, 0.f, 0.f};

    for (int k0 = 0; k0 < K; k0 += 64) {
        __syncthreads();
#pragma unroll
        for (int c = 0; c < 2; c++) {            // A: 64 rows
            int r = c * 32 + srow;
            __builtin_amdgcn_global_load_lds(
                (const __attribute__((address_space(1))) unsigned int*)
                    &A[(size_t)(row0 + r) * K + k0 + sk],
                (__attribute__((address_space(3))) unsigned int*)&As[r * 64 + pk],
                16, 0, 0);
        }
#pragma unroll
        for (int c = 0; c < 4; c++) {            // B: 128 rows
            int r = c * 32 + srow;
            __builtin_amdgcn_global_load_lds(
                (const __attribute__((address_space(1))) unsigned int*)
                    &Bt[(size_t)(col0 + r) * K + k0 + sk],
                (__attribute__((address_space(3))) unsigned int*)&Bs[r * 64 + pk],
                16, 0, 0);
        }
        __syncthreads();

#pragma unroll
        for (int kk = 0; kk < 2; kk++) {
            int xc = (((kk * 4 + quad) ^ (l15 & 7)) * 8);
            s16x8 af[2], bf[4];
#pragma unroll
            for (int mt = 0; mt < 2; mt++)
                af[mt] = *(const s16x8*)&As[(wm * 32 + mt * 16 + l15) * 64 + xc];
#pragma unroll
            for (int nt = 0; nt < 4; nt++)
                bf[nt] = *(const s16x8*)&Bs[(wn * 64 + nt * 16 + l15) * 64 + xc];
#pragma unroll
            for (int mt = 0; mt < 2; mt++)
#pragma unroll
                for (int nt = 0; nt < 4; nt++)
                    acc[mt][nt] = __builtin_amdgcn_mfma_f32_16x16x32_bf16(
                        af[mt], bf[nt], acc[mt][nt], 0, 0, 0);
        }
    }

#pragma unroll
    for (int nt = 0; nt < 4; nt++) {
        int n = col0 + wn * 64 + nt * 16 + l15;
        float bv = bias[n];
#pragma unroll
        for (int mt = 0; mt < 2; mt++)
#pragma unroll
            for (int r = 0; r < 4; r++) {
                int row = row0 + wm * 32 + mt * 16 + quad * 4 + r;
                C0[(size_t)row * N + n] = acc[mt][nt][r] + bv;
            }
    }
}

// ---------------------------------------------------------------------------
// MFMA flash attention — SWAPPED QK^T, softmax fully in-register (unchanged
// from round 17, which knocked attn out of the top-5).
// ---------------------------------------------------------------------------
__global__ __launch_bounds__(256) void attn_mfma_kernel(
    const ushort* __restrict__ Qbf,   // [B*S, E] bf16
    const ushort* __restrict__ Kbf,   // [B*S, E] bf16
    const ushort* __restrict__ Vt,    // [(b*H+h)*64+d][s] bf16, key-permuted
    const ushort* __restrict__ biasT, // causal-packed bf16 tiles
    ushort* __restrict__ Ctx)         // [B*S, E] bf16
{
    __shared__ ushort Ks[64][64];
    __shared__ ushort Vs[64][64];

    int blk = blockIdx.x;
    int bh = blk & 31;               // XCD = bh%8 -> K/V L2 locality
    int pr = blk >> 5;               // 0..15
    int b = bh >> 4, h = bh & 15;
    int tid = threadIdx.x;
    int wid = tid >> 6, lane = tid & 63;
    int l15 = lane & 15, quad = lane >> 4;

    int skey = tid >> 2;
    int scol = (tid & 3) * 16;
    int sc0 = ((((tid & 3) * 2) ^ (skey & 7)) * 8);
    int sc1 = sc0 ^ 8;
    const float scale_l2e = 0.18033688011112042f;   // 0.125 * log2(e)

    const size_t krow = (size_t)(b * S_ + skey) * E_ + h * 64 + scol; // + j0*E_
    const size_t vrow = (size_t)(bh * 64 + skey) * S_ + scol;        // + j0
    int rc0 = (quad ^ (l15 & 7)) * 8;

    for (int half = 0; half < 2; half++) {
        int qt = half ? pr : (31 - pr);
        int q0w = qt * 64 + wid * 16;
        int rowq = q0w + l15;        // this lane's q-row

        // Q fragments (consumed as the B-operand of the swapped QK^T)
        const size_t qbase = ((size_t)(b * S_ + q0w + l15)) * E_ + h * 64 + quad * 8;
        s16x8 qa0 = *(const s16x8*)&Qbf[qbase];
        s16x8 qa1 = *(const s16x8*)&Qbf[qbase + 32];

        f32x4 o[4];
#pragma unroll
        for (int dt = 0; dt < 4; dt++) o[dt] = (f32x4){0.f, 0.f, 0.f, 0.f};
        float ls = 0.f;

        // ---- preload tile 0 into registers
        float4 kr0 = ((const float4*)&Kbf[krow])[0];
        float4 kr1 = ((const float4*)&Kbf[krow])[1];
        float4 vr0 = ((const float4*)&Vt[vrow])[0];
        float4 vr1 = ((const float4*)&Vt[vrow])[1];
        const ushort* bt = &biasT[((size_t)(qt * (qt + 1) / 2) * 256 + tid) * 16];
        s16x8 bn0 = *(const s16x8*)bt;
        s16x8 bn1 = *(const s16x8*)(bt + 8);

        for (int t = 0; t <= qt; t++) {
            int j0 = t * 64;
            __syncthreads();          // prior compute done; LDS free
            *(float4*)&Ks[skey][sc0] = kr0;
            *(float4*)&Ks[skey][sc1] = kr1;
            *(float4*)&Vs[skey][sc0] = vr0;
            *(float4*)&Vs[skey][sc1] = vr1;
            s16x8 b0 = bn0, b1 = bn1;
            __syncthreads();

            // ---- prefetch tile t+1 (registers only; hides under compute)
            if (t < qt) {
                int j1 = j0 + 64;
                kr0 = ((const float4*)&Kbf[krow + (size_t)j1 * E_])[0];
                kr1 = ((const float4*)&Kbf[krow + (size_t)j1 * E_])[1];
                vr0 = ((const float4*)&Vt[vrow + j1])[0];
                vr1 = ((const float4*)&Vt[vrow + j1])[1];
                const ushort* btn = bt + (size_t)(t + 1) * 4096;
                bn0 = *(const s16x8*)btn;
                bn1 = *(const s16x8*)(btn + 8);
            }

            // ---- S^T = K Q^T : lane reg r = S[key=j0+kt*16+quad*4+r][rowq]
            f32x4 s[4];
#pragma unroll
            for (int kt = 0; kt < 4; kt++) {
                s16x8 kb0 = *(const s16x8*)&Ks[kt * 16 + l15][rc0];
                s16x8 kb1 = *(const s16x8*)&Ks[kt * 16 + l15][rc0 ^ 32];
                f32x4 acc = (f32x4){0.f, 0.f, 0.f, 0.f};
                acc = __builtin_amdgcn_mfma_f32_16x16x32_bf16(kb0, qa0, acc, 0, 0, 0);
                acc = __builtin_amdgcn_mfma_f32_16x16x32_bf16(kb1, qa1, acc, 0, 0, 0);
                s[kt] = acc;
            }

            // ---- p = exp2(s*scale + biasT); causal mask; pack pa IN REGS
            bool diag = (t == qt);
            unsigned upk[8];
#pragma unroll
            for (int kt = 0; kt < 4; kt++) {
                float pv[4];
#pragma unroll
                for (int r = 0; r < 4; r++) {
                    int idx = kt * 4 + r;
                    ushort ub = (ushort)((idx < 8) ? b0[idx] : b1[idx - 8]);
                    union { unsigned u; float f; } bc; bc.u = ((unsigned)ub) << 16;
                    float v = fmaf(s[kt][r], scale_l2e, bc.f);
                    int j = j0 + kt * 16 + quad * 4 + r;
                    float p = (diag && j > rowq) ? 0.f : fast_exp2(v);
                    ls += p;
                    pv[r] = p;
                }
                asm("v_cvt_pk_bf16_f32 %0, %1, %2"
                    : "=v"(upk[kt * 2]) : "v"(pv[0]), "v"(pv[1]));
                asm("v_cvt_pk_bf16_f32 %0, %1, %2"
                    : "=v"(upk[kt * 2 + 1]) : "v"(pv[2]), "v"(pv[3]));
            }
            uint4 ua = make_uint4(upk[0], upk[1], upk[2], upk[3]);
            uint4 ub4 = make_uint4(upk[4], upk[5], upk[6], upk[7]);
            s16x8 pa0 = *(s16x8*)&ua;
            s16x8 pa1 = *(s16x8*)&ub4;

            // ---- O += P V  (A-frag from regs; V slot order matches)
#pragma unroll
            for (int dt = 0; dt < 4; dt++) {
                s16x8 vb0 = *(const s16x8*)&Vs[dt * 16 + l15][rc0];
                s16x8 vb1 = *(const s16x8*)&Vs[dt * 16 + l15][rc0 ^ 32];
                o[dt] = __builtin_amdgcn_mfma_f32_16x16x32_bf16(pa0, vb0, o[dt], 0, 0, 0);
                o[dt] = __builtin_amdgcn_mfma_f32_16x16x32_bf16(pa1, vb1, o[dt], 0, 0, 0);
            }
        }

        // ---- row-sum reduction: quad-partial sums live per lane
        float l = ls;
        l += __shfl_xor(l, 16);
        l += __shfl_xor(l, 32);
        float inv = 1.f / l;          // row q0w + l15 total (all quads)
        float inv_l[4];
#pragma unroll
        for (int r = 0; r < 4; r++)
            inv_l[r] = __shfl(inv, quad * 4 + r);   // row sums for output rows

#pragma unroll
        for (int dt = 0; dt < 4; dt++) {
#pragma unroll
            for (int r = 0; r < 4; r++) {
                int row = q0w + quad * 4 + r;
                Ctx[((size_t)(b * S_ + row)) * E_ + h * 64 + dt * 16 + l15] =
                    f2bf(o[dt][r] * inv_l[r]);
            }
        }
    }
}

// ---------------------------------------------------------------------------
extern "C" void kernel_launch(void* const* d_in, const int* in_sizes, int n_in,
                              void* d_out, int out_size, void* d_ws, size_t ws_size,
                              hipStream_t stream) {
    const float* X     = (const float*)d_in[0];
    const float* abias = (const float*)d_in[1];
    const float* Wqkv  = (const float*)d_in[2];
    const float* bqkv  = (const float*)d_in[3];
    const float* Wproj = (const float*)d_in[4];
    const float* bproj = (const float*)d_in[5];

    const size_t plane = (size_t)B_ * S_ * E_;   // 4,194,304
    float* out  = (float*)d_out;
    float* kout = out + plane;                   // cache_key (fp32 output)
    float* vout = kout + plane;                  // cache_value (fp32 output)

    // workspace: 4 bf16 planes + weights = 42 MB (proven footprint).
    // ctxbf ALIASES xbf (X's bf16 copy is dead after the QKV GEMM).
    // biasT ALIASES wqkvt (Wqkv^T dead after the QKV GEMM; 4.3MB <= 6MB).
    ushort* xbf    = (ushort*)d_ws;
    ushort* qbf    = xbf + plane;
    ushort* kbf    = qbf + plane;
    ushort* vt     = kbf + plane;
    ushort* ctxbf  = xbf;                        // alias (see above)
    ushort* wqkvt  = vt + plane;                 // [3E][E]
    ushort* wprojt = wqkvt + (size_t)3 * E_ * E_;// [E][E]
    ushort* biasT  = wqkvt;                      // alias (see above)

    const int M = B_ * S_;

    // fused: cvtx (4096 blocks) + Wqkv^T (768) + Wproj^T (256)
    prep_fused_kernel<<<dim3(5120), 256, 0, stream>>>(
        X, xbf, Wqkv, wqkvt, Wproj, wprojt);

    // QKV GEMM with fused V-transpose epilogue (writes Vt directly)
    gemm_mfma_bt<<<dim3(3 * E_ / 128, M / 128), 256, 0, stream>>>(
        xbf, wqkvt, bqkv, M, 3 * E_, E_,
        qbf, kout, kbf, vout, vt);

    // bias pre-pack only (vtrans now fused into the GEMM)
    prep_bias_kernel<<<dim3(528), 256, 0, stream>>>(abias, biasT);

    // flash attention: 512 paired blocks; XCD = bh%8 for K/V L2 locality
    attn_mfma_kernel<<<dim3(B_ * H_ * 16), 256, 0, stream>>>(
        qbf, kbf, vt, biasT, ctxbf);

    // proj GEMM: 64x128 tiles -> 512 blocks = 2 blocks/CU
    gemm_proj64<<<dim3(E_ / 128, M / 64), 256, 0, stream>>>(
        ctxbf, wprojt, bproj, M, E_, E_, out);
}